// Round 3
// baseline (861.829 us; speedup 1.0000x reference)
//
#include <hip/hip_runtime.h>
#include <stdint.h>

namespace {

constexpr int Bn = 8;
constexpr int Sn = 2048;
constexpr int Cn = 1024;
constexpr int Mn = Bn * Sn;  // 16384

typedef float f32x4 __attribute__((ext_vector_type(4)));
typedef __bf16 bf16x8 __attribute__((ext_vector_type(8)));
typedef unsigned short us8 __attribute__((ext_vector_type(8)));

__device__ __forceinline__ unsigned short f2bf(float f) {
  uint32_t x = __float_as_uint(f);
  x += 0x7fffu + ((x >> 16) & 1u);  // round-to-nearest-even
  return (unsigned short)(x >> 16);
}
__device__ __forceinline__ float bf2f(unsigned short u) {
  return __uint_as_float(((uint32_t)u) << 16);
}

__device__ __forceinline__ void stage16(const unsigned short* g, unsigned short* l) {
  __builtin_amdgcn_global_load_lds(
      (const __attribute__((address_space(1))) void*)g,
      (__attribute__((address_space(3))) void*)l, 16, 0, 0);
}

// f32 -> (hi bf16, lo bf16) split, vectorized
__global__ __launch_bounds__(256) void k_split(const float* __restrict__ src,
                                               unsigned short* __restrict__ hi,
                                               unsigned short* __restrict__ lo, int n) {
  int stride = gridDim.x * blockDim.x;
  for (int i = blockIdx.x * blockDim.x + threadIdx.x; i * 4 < n; i += stride) {
    int j = i * 4;
    float4 v = *(const float4*)(src + j);
    ushort4 h, l;
    h.x = f2bf(v.x); l.x = f2bf(v.x - bf2f(h.x));
    h.y = f2bf(v.y); l.y = f2bf(v.y - bf2f(h.y));
    h.z = f2bf(v.z); l.z = f2bf(v.z - bf2f(h.z));
    h.w = f2bf(v.w); l.w = f2bf(v.w - bf2f(h.w));
    *(ushort4*)(hi + j) = h;
    *(ushort4*)(lo + j) = l;
  }
}

__global__ __launch_bounds__(256) void k_cast(const float* __restrict__ src,
                                              unsigned short* __restrict__ dst, int n) {
  int stride = gridDim.x * blockDim.x;
  for (int i = blockIdx.x * blockDim.x + threadIdx.x; i * 4 < n; i += stride) {
    int j = i * 4;
    float4 v = *(const float4*)(src + j);
    ushort4 h;
    h.x = f2bf(v.x); h.y = f2bf(v.y); h.z = f2bf(v.z); h.w = f2bf(v.w);
    *(ushort4*)(dst + j) = h;
  }
}

// SRC modes: 0 = bf16 hi only (global_load_lds); 1 = bf16 hi+lo (x2 global_load_lds)
template <int SRC>
__device__ __forceinline__ void stage_side(const void* G0, const void* G1,
                                           long long goff, int ld, int k0, int tbase,
                                           int t, unsigned short* Ls,
                                           unsigned short* Ls2) {
#pragma unroll
  for (int c = 0; c < 2; ++c) {
    int idx = c * 256 + t;
    int row = idx >> 2;
    int co = (idx & 3) * 8;
    long long off = goff + (long long)(tbase + row) * ld + k0 + co;
    stage16((const unsigned short*)G0 + off, Ls + idx * 8);
    if constexpr (SRC == 1) stage16((const unsigned short*)G1 + off, Ls2 + idx * 8);
  }
}

// C = A * B^T (+bias). A:[M,K], B^T:[N,K]. 128x128 tile, BK=32, 4 waves,
// 16x16x32 bf16 MFMA. Split (3-term hi/lo emulation) iff ASRC==1.
// BIAS: 0 none, 1 per-col, 2 per-row.  OUTM: 0 f32, 1 bf16, 2 split bf16 hi/lo.
template <int ASRC, int BSRC, int BIAS, int OUTM>
__global__ __launch_bounds__(256) void gemm(
    const void* __restrict__ A0, const void* __restrict__ A1,
    const void* __restrict__ B0, const void* __restrict__ B1,
    const float* __restrict__ bias, void* __restrict__ C0, void* __restrict__ C1,
    int K, int lda, int ldb, int ldc,
    long long sAz, long long sBz, long long sCz) {
  constexpr bool SPL = (ASRC == 1);
  __shared__ unsigned short smem[SPL ? 16384 : 8192];
  unsigned short* As = smem;
  unsigned short* Bs = smem + 4096;
  unsigned short* As2 = SPL ? smem + 8192 : nullptr;
  unsigned short* Bs2 = SPL ? smem + 12288 : nullptr;

  const int z = blockIdx.z;
  const long long aoff = (long long)z * sAz;
  const long long boff = (long long)z * sBz;
  const long long coff = (long long)z * sCz;
  const int tN = blockIdx.x * 128;
  const int tM = blockIdx.y * 128;
  const int t = threadIdx.x;
  const int l = t & 63;
  const int w = t >> 6;
  const int wr = w >> 1, wc = w & 1;
  const int lr = l & 15;
  const int lk = (l >> 4) * 8;

  f32x4 acc[4][4] = {};

  for (int k0 = 0; k0 < K; k0 += 32) {
    stage_side<ASRC>(A0, A1, aoff, lda, k0, tM, t, As, As2);
    stage_side<BSRC>(B0, B1, boff, ldb, k0, tN, t, Bs, Bs2);
    __syncthreads();
    bf16x8 a0[4], b0[4], a1[4], b1[4];
#pragma unroll
    for (int i = 0; i < 4; ++i) {
      a0[i] = *(const bf16x8*)&As[(wr * 64 + i * 16 + lr) * 32 + lk];
      b0[i] = *(const bf16x8*)&Bs[(wc * 64 + i * 16 + lr) * 32 + lk];
      if constexpr (SPL) {
        a1[i] = *(const bf16x8*)&As2[(wr * 64 + i * 16 + lr) * 32 + lk];
        b1[i] = *(const bf16x8*)&Bs2[(wc * 64 + i * 16 + lr) * 32 + lk];
      }
    }
#pragma unroll
    for (int mi = 0; mi < 4; ++mi)
#pragma unroll
      for (int ni = 0; ni < 4; ++ni) {
        acc[mi][ni] = __builtin_amdgcn_mfma_f32_16x16x32_bf16(a0[mi], b0[ni], acc[mi][ni], 0, 0, 0);
        if constexpr (SPL) {
          acc[mi][ni] = __builtin_amdgcn_mfma_f32_16x16x32_bf16(a0[mi], b1[ni], acc[mi][ni], 0, 0, 0);
          acc[mi][ni] = __builtin_amdgcn_mfma_f32_16x16x32_bf16(a1[mi], b0[ni], acc[mi][ni], 0, 0, 0);
        }
      }
    __syncthreads();
  }

#pragma unroll
  for (int mi = 0; mi < 4; ++mi)
#pragma unroll
    for (int ni = 0; ni < 4; ++ni)
#pragma unroll
      for (int r = 0; r < 4; ++r) {
        int rg = tM + wr * 64 + mi * 16 + (l >> 4) * 4 + r;
        int cg = tN + wc * 64 + ni * 16 + lr;
        float v = acc[mi][ni][r];
        if constexpr (BIAS == 1) v += bias[cg];
        if constexpr (BIAS == 2) v += bias[rg];
        long long off = coff + (long long)rg * ldc + cg;
        if constexpr (OUTM == 0) {
          ((float*)C0)[off] = v;
        } else if constexpr (OUTM == 1) {
          ((unsigned short*)C0)[off] = f2bf(v);
        } else {
          unsigned short h = f2bf(v);
          ((unsigned short*)C0)[off] = h;
          ((unsigned short*)C1)[off] = f2bf(v - bf2f(h));
        }
      }
}

// In-place row softmax: reads fp32 row [Sn], writes normalized bf16 attn into
// the first Sn shorts of the same row. Reads complete before first barrier,
// writes after the second -> race-free.
__global__ __launch_bounds__(256) void k_softmax(float* __restrict__ S) {
  const long long row = blockIdx.x;
  float* src = S + row * Sn;
  const int t = threadIdx.x;
  float4 v0 = *(const float4*)(src + t * 8);
  float4 v1 = *(const float4*)(src + t * 8 + 4);
  float m = fmaxf(fmaxf(fmaxf(v0.x, v0.y), fmaxf(v0.z, v0.w)),
                  fmaxf(fmaxf(v1.x, v1.y), fmaxf(v1.z, v1.w)));
#pragma unroll
  for (int off = 32; off > 0; off >>= 1) m = fmaxf(m, __shfl_xor(m, off));
  __shared__ float red[8];
  if ((t & 63) == 0) red[t >> 6] = m;
  __syncthreads();
  m = fmaxf(fmaxf(red[0], red[1]), fmaxf(red[2], red[3]));
  float e[8];
  e[0] = __expf(v0.x - m); e[1] = __expf(v0.y - m);
  e[2] = __expf(v0.z - m); e[3] = __expf(v0.w - m);
  e[4] = __expf(v1.x - m); e[5] = __expf(v1.y - m);
  e[6] = __expf(v1.z - m); e[7] = __expf(v1.w - m);
  float s = ((e[0] + e[1]) + (e[2] + e[3])) + ((e[4] + e[5]) + (e[6] + e[7]));
#pragma unroll
  for (int off = 32; off > 0; off >>= 1) s += __shfl_xor(s, off);
  if ((t & 63) == 0) red[4 + (t >> 6)] = s;
  __syncthreads();
  s = (red[4] + red[5]) + (red[6] + red[7]);
  float inv = 1.0f / s;
  us8 o;
#pragma unroll
  for (int j = 0; j < 8; ++j) o[j] = f2bf(e[j] * inv);
  *(us8*)((unsigned short*)src + t * 8) = o;
}

}  // namespace

extern "C" void kernel_launch(void* const* d_in, const int* in_sizes, int n_in,
                              void* d_out, int out_size, void* d_ws, size_t ws_size,
                              hipStream_t stream) {
  (void)in_sizes; (void)n_in; (void)out_size;
  const float* x1 = (const float*)d_in[0];
  const float* x2 = (const float*)d_in[1];
  const float* x3 = (const float*)d_in[2];
  const float* Wq = (const float*)d_in[3];
  const float* bq = (const float*)d_in[4];
  const float* Wk = (const float*)d_in[5];
  const float* bk = (const float*)d_in[6];
  const float* Wv = (const float*)d_in[7];
  const float* bv = (const float*)d_in[8];
  float* out = (float*)d_out;
  char* ws = (char*)d_ws;

  const size_t MiB = 1048576ull;
  // ws layout (MiB offsets):
  //  [0,2) wqh [2,4) wql [4,6) wkh [6,8) wkl [8,10) wvb
  //  [10,42) x1h [42,74) x1l      (aliased by kh/kl after Q-proj)
  //  [74,106) x2h [106,138) x2l
  //  [138,170) vT
  //  [170,202) x3b
  //  [202, 202+16*zc) scores (fp32)
  unsigned short* wqh = (unsigned short*)(ws);
  unsigned short* wql = (unsigned short*)(ws + 2 * MiB);
  unsigned short* wkh = (unsigned short*)(ws + 4 * MiB);
  unsigned short* wkl = (unsigned short*)(ws + 6 * MiB);
  unsigned short* wvb = (unsigned short*)(ws + 8 * MiB);
  unsigned short* x1h = (unsigned short*)(ws + 10 * MiB);
  unsigned short* x1l = (unsigned short*)(ws + 42 * MiB);
  unsigned short* x2h = (unsigned short*)(ws + 74 * MiB);
  unsigned short* x2l = (unsigned short*)(ws + 106 * MiB);
  unsigned short* vT  = (unsigned short*)(ws + 138 * MiB);
  unsigned short* x3b = (unsigned short*)(ws + 170 * MiB);
  float* S = (float*)(ws + 202 * MiB);
  unsigned short* kh = x1h;  // alias: x1 splits dead after Q projection
  unsigned short* kl = x1l;

  int zc = 0;
  for (int z = 8; z >= 1; z >>= 1)
    if (ws_size >= 202 * MiB + (size_t)z * 16 * MiB) { zc = z; break; }
  if (!zc) return;  // ws too small: visible failure (output stays zero)

  // q hi/lo interleaved per batch inside d_out: batch b = [b*8MiB,(b+1)*8MiB):
  // hi[Sn][Cn] then lo[Sn][Cn]. PV overwrites batch b only after q[b] consumed.
  unsigned short* qh = (unsigned short*)d_out;
  unsigned short* ql = (unsigned short*)((char*)d_out + 4 * MiB);
  const long long QZ = 4ll * 1024 * 1024;  // shorts per batch block

  const int nx = Mn * Cn, nw = Cn * Cn;
  k_split<<<2048, 256, 0, stream>>>(x1, x1h, x1l, nx);
  k_split<<<2048, 256, 0, stream>>>(x2, x2h, x2l, nx);
  k_cast<<<2048, 256, 0, stream>>>(x3, x3b, nx);
  k_split<<<256, 256, 0, stream>>>(Wq, wqh, wql, nw);
  k_split<<<256, 256, 0, stream>>>(Wk, wkh, wkl, nw);
  k_cast<<<256, 256, 0, stream>>>(Wv, wvb, nw);

  // Q = x1 @ Wq^T + bq  (split 3-term MFMA, split output into d_out)
  dim3 gqk(Cn / 128, Sn / 128, Bn);
  gemm<1, 1, 1, 2><<<gqk, 256, 0, stream>>>(x1h, x1l, wqh, wql, bq, qh, ql,
                                            Cn, Cn, Cn, Cn,
                                            (long long)Sn * Cn, 0, QZ);
  // K = x2 @ Wk^T + bk -> kh,kl (over dead x1 splits)
  gemm<1, 1, 1, 2><<<gqk, 256, 0, stream>>>(x2h, x2l, wkh, wkl, bk, kh, kl,
                                            Cn, Cn, Cn, Cn,
                                            (long long)Sn * Cn, 0, (long long)Sn * Cn);
  // vT[d][b*Sn+s] = (x3 @ Wv^T + bv)^T : A=Wv(bf16), B^T=x3(bf16), row bias
  dim3 gv(Mn / 128, Cn / 128, 1);
  gemm<0, 0, 2, 1><<<gv, 256, 0, stream>>>(wvb, nullptr, x3b, nullptr, bv, vT, nullptr,
                                           Cn, Cn, Cn, Mn, 0, 0, 0);

  for (int b0 = 0; b0 < Bn; b0 += zc) {
    // scores[b] = q[b] @ k[b]^T (split precision, fp32 out, NO 1/sqrt(d))
    dim3 gs(Sn / 128, Sn / 128, zc);
    gemm<1, 1, 0, 0><<<gs, 256, 0, stream>>>(
        qh + (long long)b0 * QZ, ql + (long long)b0 * QZ,
        kh + (long long)b0 * Sn * Cn, kl + (long long)b0 * Sn * Cn, nullptr,
        S, nullptr, Cn, Cn, Cn, Sn, QZ, (long long)Sn * Cn, (long long)Sn * Sn);
    // in-place softmax -> bf16 attn rows (row stride becomes 2*Sn shorts)
    k_softmax<<<zc * Sn, 256, 0, stream>>>(S);
    // out[b] = attn[b] @ v[b] : A=attn (bf16, lda 2*Sn), B^T=vT cols b*Sn..
    dim3 gp(Cn / 128, Sn / 128, zc);
    gemm<0, 0, 0, 0><<<gp, 256, 0, stream>>>(
        (unsigned short*)S, nullptr, vT + (long long)b0 * Sn, nullptr, nullptr,
        out + (long long)b0 * Sn * Cn, nullptr,
        Sn, 2 * Sn, Mn, Cn,
        (long long)Sn * Sn * 2, (long long)Sn, (long long)Sn * Cn);
  }
}

// Round 4
// 759.647 us; speedup vs baseline: 1.1345x; 1.1345x over previous
//
#include <hip/hip_runtime.h>
#include <stdint.h>

namespace {

constexpr int Bn = 8;
constexpr int Sn = 2048;
constexpr int Cn = 1024;
constexpr int Mn = Bn * Sn;  // 16384

typedef float f32x4 __attribute__((ext_vector_type(4)));
typedef __bf16 bf16x8 __attribute__((ext_vector_type(8)));
typedef unsigned short us8 __attribute__((ext_vector_type(8)));

__device__ __forceinline__ unsigned short f2bf(float f) {
  uint32_t x = __float_as_uint(f);
  x += 0x7fffu + ((x >> 16) & 1u);  // round-to-nearest-even
  return (unsigned short)(x >> 16);
}
__device__ __forceinline__ float bf2f(unsigned short u) {
  return __uint_as_float(((uint32_t)u) << 16);
}

__device__ __forceinline__ void stage16(const unsigned short* g, unsigned short* l) {
  __builtin_amdgcn_global_load_lds(
      (const __attribute__((address_space(1))) void*)g,
      (__attribute__((address_space(3))) void*)l, 16, 0, 0);
}

// f32 -> (hi bf16, lo bf16) split, vectorized
__global__ __launch_bounds__(256) void k_split(const float* __restrict__ src,
                                               unsigned short* __restrict__ hi,
                                               unsigned short* __restrict__ lo, int n) {
  int stride = gridDim.x * blockDim.x;
  for (int i = blockIdx.x * blockDim.x + threadIdx.x; i * 4 < n; i += stride) {
    int j = i * 4;
    float4 v = *(const float4*)(src + j);
    ushort4 h, l;
    h.x = f2bf(v.x); l.x = f2bf(v.x - bf2f(h.x));
    h.y = f2bf(v.y); l.y = f2bf(v.y - bf2f(h.y));
    h.z = f2bf(v.z); l.z = f2bf(v.z - bf2f(h.z));
    h.w = f2bf(v.w); l.w = f2bf(v.w - bf2f(h.w));
    *(ushort4*)(hi + j) = h;
    *(ushort4*)(lo + j) = l;
  }
}

// concat bq||bk into ws
__global__ __launch_bounds__(256) void k_bias2(const float* __restrict__ a,
                                               const float* __restrict__ b,
                                               float* __restrict__ dst) {
  int t = threadIdx.x + blockIdx.x * 256;
  if (t < Cn) { dst[t] = a[t]; dst[Cn + t] = b[t]; }
}

// SRC modes for one GEMM operand side:
//   0 = bf16 hi only        (global_load_lds)
//   1 = bf16 hi + lo        (global_load_lds x2)
//   3 = fp32 -> hi only     (reg stage + convert + ds_write)
template <int SRC>
__device__ __forceinline__ void stage_side(const void* G0, const void* G1,
                                           long long goff, int ld, int k0, int tbase,
                                           int t, unsigned short* Ls,
                                           unsigned short* Ls2) {
#pragma unroll
  for (int c = 0; c < 2; ++c) {
    int idx = c * 256 + t;
    int row = idx >> 2;
    int co = (idx & 3) * 8;
    long long off = goff + (long long)(tbase + row) * ld + k0 + co;
    if constexpr (SRC <= 1) {
      stage16((const unsigned short*)G0 + off, Ls + idx * 8);
      if constexpr (SRC == 1) stage16((const unsigned short*)G1 + off, Ls2 + idx * 8);
    } else {
      const float* g = (const float*)G0 + off;
      float4 u0 = *(const float4*)g;
      float4 u1 = *(const float4*)(g + 4);
      float f[8] = {u0.x, u0.y, u0.z, u0.w, u1.x, u1.y, u1.z, u1.w};
      us8 h;
#pragma unroll
      for (int j = 0; j < 8; ++j) h[j] = f2bf(f[j]);
      *(us8*)&Ls[idx * 8] = h;
    }
  }
}

// C = A * B^T (+bias). A:[M,K], B^T:[N,K]. 128x128 tile, BK=32, 4 waves,
// 16x16x32 bf16 MFMA. Split (3-term hi/lo emulation) iff ASRC==1.
// BIAS: 0 none, 1 per-col, 2 per-row.
// OUTM: 0 f32, 1 bf16, 3 merged-QK split output:
//   rows [0,Mn)  -> q: hi/lo interleaved per batch into C0 (d_out)
//   rows [Mn,2Mn)-> k: hi into C2, lo into C3; B side/bias offset by sBz / Cn.
template <int ASRC, int BSRC, int BIAS, int OUTM>
__global__ __launch_bounds__(256) void gemm(
    const void* __restrict__ A0, const void* __restrict__ A1,
    const void* __restrict__ B0, const void* __restrict__ B1,
    const float* __restrict__ bias, void* __restrict__ C0, void* __restrict__ C2,
    void* __restrict__ C3,
    int K, int lda, int ldb, int ldc,
    long long sAz, long long sBz, long long sCz) {
  constexpr bool SPL = (ASRC == 1);
  __shared__ unsigned short smem[SPL ? 16384 : 8192];
  unsigned short* As = smem;
  unsigned short* Bs = smem + 4096;
  unsigned short* As2 = SPL ? smem + 8192 : nullptr;
  unsigned short* Bs2 = SPL ? smem + 12288 : nullptr;

  const int z = blockIdx.z;
  const int tN = blockIdx.x * 128;
  const int tM = blockIdx.y * 128;
  const int side = (OUTM == 3) ? (tM >= Mn) : 0;
  const long long aoff = (long long)z * sAz;
  const long long boff = (OUTM == 3) ? (side ? sBz : 0) : (long long)z * sBz;
  const long long coff = (long long)z * sCz;
  const float* biasp = (OUTM == 3) ? bias + side * Cn : bias;
  const int t = threadIdx.x;
  const int l = t & 63;
  const int w = t >> 6;
  const int wr = w >> 1, wc = w & 1;
  const int lr = l & 15;
  const int lk = (l >> 4) * 8;

  f32x4 acc[4][4] = {};

  for (int k0 = 0; k0 < K; k0 += 32) {
    stage_side<ASRC>(A0, A1, aoff, lda, k0, tM, t, As, As2);
    stage_side<BSRC>(B0, B1, boff, ldb, k0, tN, t, Bs, Bs2);
    __syncthreads();
    bf16x8 a0[4], b0[4], a1[4], b1[4];
#pragma unroll
    for (int i = 0; i < 4; ++i) {
      a0[i] = *(const bf16x8*)&As[(wr * 64 + i * 16 + lr) * 32 + lk];
      b0[i] = *(const bf16x8*)&Bs[(wc * 64 + i * 16 + lr) * 32 + lk];
      if constexpr (SPL) {
        a1[i] = *(const bf16x8*)&As2[(wr * 64 + i * 16 + lr) * 32 + lk];
        b1[i] = *(const bf16x8*)&Bs2[(wc * 64 + i * 16 + lr) * 32 + lk];
      }
    }
#pragma unroll
    for (int mi = 0; mi < 4; ++mi)
#pragma unroll
      for (int ni = 0; ni < 4; ++ni) {
        acc[mi][ni] = __builtin_amdgcn_mfma_f32_16x16x32_bf16(a0[mi], b0[ni], acc[mi][ni], 0, 0, 0);
        if constexpr (SPL) {
          acc[mi][ni] = __builtin_amdgcn_mfma_f32_16x16x32_bf16(a0[mi], b1[ni], acc[mi][ni], 0, 0, 0);
          acc[mi][ni] = __builtin_amdgcn_mfma_f32_16x16x32_bf16(a1[mi], b0[ni], acc[mi][ni], 0, 0, 0);
        }
      }
    __syncthreads();
  }

#pragma unroll
  for (int mi = 0; mi < 4; ++mi)
#pragma unroll
    for (int ni = 0; ni < 4; ++ni)
#pragma unroll
      for (int r = 0; r < 4; ++r) {
        int rg = tM + wr * 64 + mi * 16 + (l >> 4) * 4 + r;
        int cg = tN + wc * 64 + ni * 16 + lr;
        float v = acc[mi][ni][r];
        if constexpr (BIAS == 1) v += biasp[cg];
        if constexpr (BIAS == 2) v += biasp[rg];
        if constexpr (OUTM == 0) {
          ((float*)C0)[coff + (long long)rg * ldc + cg] = v;
        } else if constexpr (OUTM == 1) {
          ((unsigned short*)C0)[coff + (long long)rg * ldc + cg] = f2bf(v);
        } else {  // OUTM == 3
          unsigned short h = f2bf(v);
          unsigned short lo = f2bf(v - bf2f(h));
          int rr = rg - side * Mn;
          if (!side) {
            // q: batch block = 4M shorts (8 MiB): hi [0,2M), lo [2M,4M)
            long long off = (long long)(rr >> 11) * 4194304ll +
                            (long long)(rr & 2047) * Cn + cg;
            ((unsigned short*)C0)[off] = h;
            ((unsigned short*)C0)[off + 2097152ll] = lo;
          } else {
            long long off = (long long)rr * Cn + cg;
            ((unsigned short*)C2)[off] = h;
            ((unsigned short*)C3)[off] = lo;
          }
        }
      }
}

// In-place row softmax: reads fp32 row [Sn], writes normalized bf16 attn into
// the first Sn shorts of the same row. Reads complete before first barrier,
// writes after the second -> race-free.
__global__ __launch_bounds__(256) void k_softmax(float* __restrict__ S) {
  const long long row = blockIdx.x;
  float* src = S + row * Sn;
  const int t = threadIdx.x;
  float4 v0 = *(const float4*)(src + t * 8);
  float4 v1 = *(const float4*)(src + t * 8 + 4);
  float m = fmaxf(fmaxf(fmaxf(v0.x, v0.y), fmaxf(v0.z, v0.w)),
                  fmaxf(fmaxf(v1.x, v1.y), fmaxf(v1.z, v1.w)));
#pragma unroll
  for (int off = 32; off > 0; off >>= 1) m = fmaxf(m, __shfl_xor(m, off));
  __shared__ float red[8];
  if ((t & 63) == 0) red[t >> 6] = m;
  __syncthreads();
  m = fmaxf(fmaxf(red[0], red[1]), fmaxf(red[2], red[3]));
  float e[8];
  e[0] = __expf(v0.x - m); e[1] = __expf(v0.y - m);
  e[2] = __expf(v0.z - m); e[3] = __expf(v0.w - m);
  e[4] = __expf(v1.x - m); e[5] = __expf(v1.y - m);
  e[6] = __expf(v1.z - m); e[7] = __expf(v1.w - m);
  float s = ((e[0] + e[1]) + (e[2] + e[3])) + ((e[4] + e[5]) + (e[6] + e[7]));
#pragma unroll
  for (int off = 32; off > 0; off >>= 1) s += __shfl_xor(s, off);
  if ((t & 63) == 0) red[4 + (t >> 6)] = s;
  __syncthreads();
  s = (red[4] + red[5]) + (red[6] + red[7]);
  float inv = 1.0f / s;
  us8 o;
#pragma unroll
  for (int j = 0; j < 8; ++j) o[j] = f2bf(e[j] * inv);
  *(us8*)((unsigned short*)src + t * 8) = o;
}

}  // namespace

extern "C" void kernel_launch(void* const* d_in, const int* in_sizes, int n_in,
                              void* d_out, int out_size, void* d_ws, size_t ws_size,
                              hipStream_t stream) {
  (void)in_sizes; (void)n_in; (void)out_size;
  const float* x1 = (const float*)d_in[0];
  const float* x2 = (const float*)d_in[1];
  const float* x3 = (const float*)d_in[2];
  const float* Wq = (const float*)d_in[3];
  const float* bq = (const float*)d_in[4];
  const float* Wk = (const float*)d_in[5];
  const float* bk = (const float*)d_in[6];
  const float* Wv = (const float*)d_in[7];
  const float* bv = (const float*)d_in[8];
  float* out = (float*)d_out;
  char* ws = (char*)d_ws;

  const size_t MiB = 1048576ull;
  // ws layout (MiB offsets), NEED = 236 MiB (round-3 zc probe proved ws>=266):
  //  [0,2) wqh [2,4) wkh [4,6) wql [6,8) wkl [8,~8.01) bias_cat
  //  [12,44) x1h [44,76) x2h   -> virtual A-hi [32768,1024]
  //  [76,108) x1l [108,140) x2l -> virtual A-lo
  //  [140,172) kh [172,204) kl [204,236) vT
  //  scores fp32 [12,140) overlays x1/x2 splits (dead after merged QK-proj)
  unsigned short* wqh = (unsigned short*)(ws);
  unsigned short* wql = (unsigned short*)(ws + 4 * MiB);
  float* bias_cat = (float*)(ws + 8 * MiB);
  unsigned short* x1h = (unsigned short*)(ws + 12 * MiB);
  unsigned short* x2h = (unsigned short*)(ws + 44 * MiB);
  unsigned short* x1l = (unsigned short*)(ws + 76 * MiB);
  unsigned short* x2l = (unsigned short*)(ws + 108 * MiB);
  unsigned short* kh  = (unsigned short*)(ws + 140 * MiB);
  unsigned short* kl  = (unsigned short*)(ws + 172 * MiB);
  unsigned short* vT  = (unsigned short*)(ws + 204 * MiB);
  float* S = (float*)(ws + 12 * MiB);
  if (ws_size < 236 * MiB) return;  // visible failure => ws probe

  // q hi/lo interleaved per batch inside d_out; fully consumed by the single
  // QK^T dispatch before PV overwrites d_out.
  unsigned short* qh = (unsigned short*)d_out;
  const long long QZ = 4ll * 1024 * 1024;  // shorts per q batch block

  const int nx = Mn * Cn, nw = Cn * Cn;
  k_split<<<2048, 256, 0, stream>>>(x1, x1h, x1l, nx);
  k_split<<<2048, 256, 0, stream>>>(x2, x2h, x2l, nx);
  k_split<<<256, 256, 0, stream>>>(Wq, wqh, wql, nw);
  k_split<<<256, 256, 0, stream>>>(Wk, wqh + 1048576, wql + 1048576, nw);
  k_bias2<<<4, 256, 0, stream>>>(bq, bk, bias_cat);

  // Merged Q+K projection: virtual M=32768, one 2048-block dispatch.
  // side-stride sBz = 1M shorts (wqh->wkh, wql->wkl).
  dim3 gqk(Cn / 128, (2 * Mn) / 128, 1);
  gemm<1, 1, 1, 3><<<gqk, 256, 0, stream>>>(x1h, x1l, wqh, wql, bias_cat,
                                            qh, kh, kl,
                                            Cn, Cn, Cn, Cn, 0, 1048576ll, 0);
  // vT[d][s] = (x3 @ Wv^T + bv)^T : A=Wv(fp32 reg-staged), B^T=x3, row bias
  dim3 gv(Mn / 128, Cn / 128, 1);
  gemm<3, 3, 2, 1><<<gv, 256, 0, stream>>>(Wv, nullptr, x3, nullptr, bv,
                                           vT, nullptr, nullptr,
                                           Cn, Cn, Cn, Mn, 0, 0, 0);
  // scores[b] = q[b] @ k[b]^T (split precision, fp32 out, NO 1/sqrt(d))
  dim3 gs(Sn / 128, Sn / 128, Bn);
  gemm<1, 1, 0, 0><<<gs, 256, 0, stream>>>(
      qh, qh + 2097152, kh, kl, nullptr, S, nullptr, nullptr,
      Cn, Cn, Cn, Sn, QZ, (long long)Sn * Cn, (long long)Sn * Sn);
  // in-place softmax -> bf16 attn rows (row stride becomes 2*Sn shorts)
  k_softmax<<<Mn, 256, 0, stream>>>(S);
  // out[b] = attn[b] @ v[b] : A=attn (bf16, lda 2*Sn), B^T=vT cols b*Sn..
  dim3 gp(Cn / 128, Sn / 128, Bn);
  gemm<0, 0, 0, 0><<<gp, 256, 0, stream>>>(
      (unsigned short*)S, nullptr, vT, nullptr, nullptr,
      out, nullptr, nullptr,
      Sn, 2 * Sn, Mn, Cn,
      (long long)Sn * Sn * 2, (long long)Sn, (long long)Sn * Cn);
}